// Round 5
// baseline (19039.095 us; speedup 1.0000x reference)
//
#include <hip/hip_runtime.h>
#include <hip/hip_cooperative_groups.h>
namespace cg = cooperative_groups;

typedef unsigned short u16;
typedef unsigned int   u32;
typedef _Float16 f16;
typedef f16   f16x8 __attribute__((ext_vector_type(8)));
typedef float f32x4 __attribute__((ext_vector_type(4)));

#define B_  64
#define L_  384
#define CS  512   // SRC_DIM
#define H_  512
#define E_  256
#define NC  250
#define T_  127

__device__ __forceinline__ float h2f(u16 u){ f16 h; __builtin_memcpy(&h,&u,2); return (float)h; }
__device__ __forceinline__ u16  f2h(float f){ f16 h=(f16)f; u16 u; __builtin_memcpy(&u,&h,2); return u; }
__device__ __forceinline__ float wredsum(float v){
#pragma unroll
  for (int o=32;o>0;o>>=1) v += __shfl_down(v, o, 64);
  return v;
}
__device__ __forceinline__ float tanh_f(float x){
  x = fminf(fmaxf(x, -15.f), 15.f);
  float e = __expf(2.f*x);
  return (e-1.f)/(e+1.f);
}
__device__ __forceinline__ float sigm_f(float x){
  x = fminf(fmaxf(x, -30.f), 30.f);
  return 1.f/(1.f+__expf(-x));
}

// ---------------- one-time converters ----------------
__global__ __launch_bounds__(256) void k_cvt(const float* __restrict__ in, f16* __restrict__ o, int n){
  int i = blockIdx.x*256 + threadIdx.x;
  if (i < n) o[i] = (f16)in[i];
}
__global__ __launch_bounds__(256) void k_packwg(const float* __restrict__ Wih,
    const float* __restrict__ Whh, f16* __restrict__ Wg){
  int i = blockIdx.x*256 + threadIdx.x;   // over 2048*1280
  if (i < 2048*1280){
    int r = i / 1280, c = i - r*1280;
    float v = (c < 768) ? Wih[(size_t)r*768 + c] : Whh[(size_t)r*512 + (c-768)];
    Wg[i] = (f16)v;
  }
}
__global__ __launch_bounds__(256) void k_initx(const int* __restrict__ text,
    const float* __restrict__ embt, f16* __restrict__ X0){
  int b = blockIdx.x, col = threadIdx.x;
  int tok = text[b*T_];
  X0[(size_t)b*1280 + 512 + col] = (f16)embt[(size_t)tok*E_ + col];
}

// ---------------- GEMM1: src_feat = src @ Wi2h^T (f32 in, f16 out), 128x128 tiles
__global__ __launch_bounds__(256) void gemm_srcfeat(
    const float* __restrict__ A, const float* __restrict__ W, u16* __restrict__ Cd,
    int M, int N, int K)
{
  __shared__ float As[8][128+4];
  __shared__ float Ws[8][128+4];
  const int tid = threadIdx.x;
  const int bm = blockIdx.x * 128;
  const int bn = blockIdx.y * 128;
  const int lr = tid >> 1;
  const int lc = (tid & 1) * 4;
  const int ty = tid >> 4, tx = tid & 15;
  float acc[8][8];
#pragma unroll
  for (int i=0;i<8;i++)
#pragma unroll
    for (int j=0;j<8;j++) acc[i][j]=0.f;

  for (int k0=0;k0<K;k0+=8){
    float4 va = *(const float4*)(A + (size_t)(bm+lr)*K + k0 + lc);
    float4 vw = *(const float4*)(W + (size_t)(bn+lr)*K + k0 + lc);
    As[lc+0][lr]=va.x; As[lc+1][lr]=va.y; As[lc+2][lr]=va.z; As[lc+3][lr]=va.w;
    Ws[lc+0][lr]=vw.x; Ws[lc+1][lr]=vw.y; Ws[lc+2][lr]=vw.z; Ws[lc+3][lr]=vw.w;
    __syncthreads();
#pragma unroll
    for (int k=0;k<8;k++){
      float a[8], w[8];
#pragma unroll
      for (int i=0;i<8;i++) a[i]=As[k][ty*8+i];
#pragma unroll
      for (int j=0;j<8;j++) w[j]=Ws[k][tx*8+j];
#pragma unroll
      for (int i=0;i<8;i++)
#pragma unroll
        for (int j=0;j<8;j++) acc[i][j] += a[i]*w[j];
    }
    __syncthreads();
  }
#pragma unroll
  for (int i=0;i<8;i++){
    int m = bm + ty*8 + i;
    u16* cp = Cd + (size_t)m*N + bn + tx*8;
    ushort4 o0, o1;
    o0.x=f2h(acc[i][0]); o0.y=f2h(acc[i][1]); o0.z=f2h(acc[i][2]); o0.w=f2h(acc[i][3]);
    o1.x=f2h(acc[i][4]); o1.y=f2h(acc[i][5]); o1.z=f2h(acc[i][6]); o1.w=f2h(acc[i][7]);
    *(ushort4*)cp = o0;
    *(ushort4*)(cp+4) = o1;
  }
}

// ---------------- GEMM2: probs = hs @ Wgen^T + bgen (A f16, W f32, out f32)
__global__ __launch_bounds__(256) void gemm_probs(
    const u16* __restrict__ A, const float* __restrict__ W, const float* __restrict__ bias,
    float* __restrict__ Cd, int M, int N, int K)
{
  __shared__ float As[16][64+1];
  __shared__ float Ws[16][64+1];
  const int tid = threadIdx.x;
  const int bm = blockIdx.x*64, bn = blockIdx.y*64;
  const int lr = tid>>2;
  const int lc = (tid&3)*4;
  const int ty = tid>>4, tx = tid&15;
  float acc[4][4];
#pragma unroll
  for (int i=0;i<4;i++)
#pragma unroll
    for (int j=0;j<4;j++) acc[i][j]=0.f;

  for (int k0=0;k0<K;k0+=16){
    ushort4 va = *(const ushort4*)(A + (size_t)(bm+lr)*K + k0 + lc);
    As[lc+0][lr]=h2f(va.x); As[lc+1][lr]=h2f(va.y); As[lc+2][lr]=h2f(va.z); As[lc+3][lr]=h2f(va.w);
    int n = bn + lr;
    if (n < N){
      float4 vw = *(const float4*)(W + (size_t)n*K + k0 + lc);
      Ws[lc+0][lr]=vw.x; Ws[lc+1][lr]=vw.y; Ws[lc+2][lr]=vw.z; Ws[lc+3][lr]=vw.w;
    } else {
      Ws[lc+0][lr]=0.f; Ws[lc+1][lr]=0.f; Ws[lc+2][lr]=0.f; Ws[lc+3][lr]=0.f;
    }
    __syncthreads();
#pragma unroll
    for (int k=0;k<16;k++){
      float a[4], w[4];
#pragma unroll
      for (int i=0;i<4;i++) a[i]=As[k][ty*4+i];
#pragma unroll
      for (int j=0;j<4;j++) w[j]=Ws[k][tx*4+j];
#pragma unroll
      for (int i=0;i<4;i++)
#pragma unroll
        for (int j=0;j<4;j++) acc[i][j] += a[i]*w[j];
    }
    __syncthreads();
  }
#pragma unroll
  for (int i=0;i<4;i++){
    int m = bm + ty*4 + i;
#pragma unroll
    for (int j=0;j<4;j++){
      int n = bn + tx*4 + j;
      if (n < N) Cd[(size_t)m*N + n] = acc[i][j] + bias[n];
    }
  }
}

// ---------------- persistent cooperative recurrence kernel ----------------
// 64 blocks x 512 threads. Per step:
//   Phase B (all 64 blocks; block = batch b): proj (block-local, Wh2h L2-hot)
//     -> logits -> softmax -> ctx -> X ctx slice.   [grid sync]
//   Phase C (blocks 0..15): MFMA gates GEMM (2 j-tiles/block) + fused cell
//     update -> cbuf, Xn h slice, hs; block 16: emb prep for t+1. [grid sync]
__global__ __launch_bounds__(512) void k_loop(
    const float* __restrict__ src, const int* __restrict__ text,
    const float* __restrict__ embt,
    const f16* __restrict__ WhF, const float* __restrict__ bh2h,
    const float* __restrict__ wsc,
    const f16* __restrict__ WgF, const float* __restrict__ b_ih,
    const float* __restrict__ b_hh,
    const u16* __restrict__ sf, float* __restrict__ cbuf,
    f16* __restrict__ X0, f16* __restrict__ X1, u16* __restrict__ hs)
{
  cg::grid_group grid = cg::this_grid();
  __shared__ float smem[8192];   // 32 KB, re-purposed per phase
  float* sh_h    = smem;          // [512]
  float* sh_proj = smem + 512;    // [512]
  float* sh_wsc  = smem + 1024;   // [512]
  float* sh_al   = smem + 1536;   // [384]
  float* sh_red  = smem + 1920;   // [8]

  const int tid  = threadIdx.x;
  const int w    = tid >> 6, lane = tid & 63;
  const int quad = lane >> 4, l16 = lane & 15;
  const int blk  = blockIdx.x;

  f16* Xc = X0; f16* Xn = X1;
  for (int t = 0; t < T_; ++t){
    // ================= Phase B =================
    {
      const int b = blk;
      if (tid < 64){
        f16x8 hv = *(const f16x8*)(Xc + (size_t)b*1280 + 768 + tid*8);
#pragma unroll
        for (int i=0;i<8;i++) sh_h[tid*8+i] = (float)hv[i];
      }
      sh_wsc[tid] = wsc[tid];
      __syncthreads();
      // proj[tid] = dot(Wh2h[tid,:], h) + bh2h[tid]
      {
        const f16* wr = WhF + (size_t)tid*512;
        float acc = 0.f;
#pragma unroll 8
        for (int k=0;k<512;k+=8){
          f16x8 wv8 = *(const f16x8*)(wr + k);
#pragma unroll
          for (int i=0;i<8;i++) acc += (float)wv8[i]*sh_h[k+i];
        }
        sh_proj[tid] = acc + bh2h[tid];
      }
      __syncthreads();
      // logits: wave w covers l in [w*48, w*48+48)
      {
        float pr[8], wr8[8];
#pragma unroll
        for (int i=0;i<8;i++){ pr[i]=sh_proj[lane*8+i]; wr8[i]=sh_wsc[lane*8+i]; }
        for (int li=0; li<48; ++li){
          int l = w*48 + li;
          const u16* sp = sf + (((size_t)(b*L_ + l))<<9) + lane*8;
          ushort4 s0=*(const ushort4*)sp, s1=*(const ushort4*)(sp+4);
          float v = tanh_f(h2f(s0.x)+pr[0])*wr8[0] + tanh_f(h2f(s0.y)+pr[1])*wr8[1]
                  + tanh_f(h2f(s0.z)+pr[2])*wr8[2] + tanh_f(h2f(s0.w)+pr[3])*wr8[3]
                  + tanh_f(h2f(s1.x)+pr[4])*wr8[4] + tanh_f(h2f(s1.y)+pr[5])*wr8[5]
                  + tanh_f(h2f(s1.z)+pr[6])*wr8[6] + tanh_f(h2f(s1.w)+pr[7])*wr8[7];
          v = wredsum(v);
          if (lane==0) sh_al[l] = v;
        }
      }
      __syncthreads();
      // softmax over 384 (waves 0..5 hold one value per thread)
      float vl = (tid < 384) ? sh_al[tid] : -1e30f;
      float mm = vl;
#pragma unroll
      for (int o=32;o>0;o>>=1) mm = fmaxf(mm, __shfl_down(mm,o,64));
      if (tid<384 && lane==0) sh_red[w] = mm;
      __syncthreads();
      if (tid==0){
        float m = sh_red[0];
#pragma unroll
        for (int i=1;i<6;i++) m = fmaxf(m, sh_red[i]);
        sh_red[6] = m;
      }
      __syncthreads();
      float M = sh_red[6];
      float e_l = 0.f;
      if (tid<384){ e_l = __expf(vl - M); sh_al[tid] = e_l; }
      float ss = e_l;
#pragma unroll
      for (int o=32;o>0;o>>=1) ss += __shfl_down(ss,o,64);
      if (tid<384 && lane==0) sh_red[w] = ss;
      __syncthreads();
      if (tid==0){
        float s = 0.f;
#pragma unroll
        for (int i=0;i<6;i++) s += sh_red[i];
        sh_red[7] = 1.f/s;
      }
      __syncthreads();
      float inv = sh_red[7];
      // ctx: thread = column c
      {
        const float* sp = src + ((size_t)b*L_)*512 + tid;
        float acc = 0.f;
#pragma unroll 4
        for (int l=0;l<L_;l++) acc += sh_al[l]*sp[(size_t)l*512];
        Xc[(size_t)b*1280 + tid] = (f16)(acc*inv);
      }
    }
    grid.sync();
    // ================= Phase C =================
    if (blk < 16){
      float (*gbuf)[4][64][16] = (float(*)[4][64][16])smem;
      const int wv = w>>2, g = w&3;
      const int j = blk*2 + wv;
      const int row = g*512 + j*16 + l16;
      const f16* bp  = WgF + (size_t)row*1280 + quad*8;
      const f16* ap0 = Xc  + (size_t)l16*1280 + quad*8;
      f32x4 acc[4] = {};
      for (int k0=0;k0<1280;k0+=32){
        f16x8 bfr = *(const f16x8*)(bp + k0);
#pragma unroll
        for (int f=0;f<4;f++){
          f16x8 afr = *(const f16x8*)(ap0 + (size_t)f*16*1280 + k0);
          acc[f] = __builtin_amdgcn_mfma_f32_16x16x32_f16(afr, bfr, acc[f], 0,0,0);
        }
      }
#pragma unroll
      for (int f=0;f<4;f++)
#pragma unroll
        for (int r=0;r<4;r++)
          gbuf[wv][g][f*16+quad*4+r][l16] = acc[f][r];
      __syncthreads();
#pragma unroll
      for (int i=0;i<4;i++){
        int cidx = tid + i*512;          // 0..2047 = 2 j-tiles x 64 b x 16 h
        int jj = cidx >> 10, rem = cidx & 1023;
        int b2 = rem >> 4, hl = rem & 15;
        int hg = (blk*2+jj)*16 + hl;
        float gi = gbuf[jj][0][b2][hl] + b_ih[hg]      + b_hh[hg];
        float gf = gbuf[jj][1][b2][hl] + b_ih[512+hg]  + b_hh[512+hg];
        float gg = gbuf[jj][2][b2][hl] + b_ih[1024+hg] + b_hh[1024+hg];
        float go = gbuf[jj][3][b2][hl] + b_ih[1536+hg] + b_hh[1536+hg];
        float fi=sigm_f(gi), ff=sigm_f(gf), fg=tanh_f(gg), fo=sigm_f(go);
        size_t ci = ((size_t)b2<<9) + hg;
        float cn = ff*cbuf[ci] + fi*fg;
        float hn = fo*tanh_f(cn);
        cbuf[ci] = cn;
        Xn[(size_t)b2*1280 + 768 + hg] = (f16)hn;
        hs[(((size_t)(b2*T_ + t))<<9) + hg] = f2h(hn);
      }
    } else if (blk == 16 && (t+1) < T_){
#pragma unroll
      for (int i=0;i<32;i++){
        int e = tid + i*512;             // 0..16383 = 64 b x 256 cols
        int b2 = e >> 8, col = e & 255;
        int tok = text[b2*T_ + t + 1];
        Xn[(size_t)b2*1280 + 512 + col] = (f16)embt[(size_t)tok*E_ + col];
      }
    }
    grid.sync();
    f16* tmp = Xc; Xc = Xn; Xn = tmp;
  }
}

extern "C" void kernel_launch(void* const* d_in, const int* in_sizes, int n_in,
                              void* d_out, int out_size, void* d_ws, size_t ws_size,
                              hipStream_t stream)
{
  const float* src   = (const float*)d_in[0];
  const int*   text  = (const int*)d_in[1];
  const float* embt  = (const float*)d_in[2];
  const float* Wi2h  = (const float*)d_in[3];
  const float* Wh2h  = (const float*)d_in[4];
  const float* bh2h  = (const float*)d_in[5];
  const float* wsc   = (const float*)d_in[6];
  const float* W_ih  = (const float*)d_in[7];
  const float* b_ih  = (const float*)d_in[8];
  const float* W_hh  = (const float*)d_in[9];
  const float* b_hh  = (const float*)d_in[10];
  const float* Wgen  = (const float*)d_in[11];
  const float* bgen  = (const float*)d_in[12];
  float* out = (float*)d_out;

  // Workspace layout (~40 MB)
  char* p = (char*)d_ws;
  u16*  sf    = (u16*)p;              p += (size_t)B_*L_*H_*2;     // 25.2 MB f16
  u16*  hs    = (u16*)p;              p += (size_t)B_*T_*H_*2;     //  8.3 MB f16
  f16*  WhF   = (f16*)p;              p += (size_t)H_*H_*2;        //  0.5 MB
  f16*  WgF   = (f16*)p;              p += (size_t)2048*1280*2;    //  5.2 MB
  f16*  X0    = (f16*)p;              p += (size_t)B_*1280*2;      //  160 KB
  f16*  X1    = (f16*)p;              p += (size_t)B_*1280*2;
  float* cbuf = (float*)p;            p += (size_t)B_*H_*4;

  hipMemsetAsync(X0,   0, (size_t)B_*1280*2, stream);
  hipMemsetAsync(cbuf, 0, (size_t)B_*H_*4, stream);

  k_cvt   <<<(H_*H_+255)/256, 256, 0, stream>>>(Wh2h, WhF, H_*H_);
  k_packwg<<<(2048*1280+255)/256, 256, 0, stream>>>(W_ih, W_hh, WgF);
  k_initx <<<B_, 256, 0, stream>>>(text, embt, X0);

  dim3 g1(B_*L_/128, H_/128);
  gemm_srcfeat<<<g1, 256, 0, stream>>>(src, Wi2h, sf, B_*L_, H_, CS);

  // persistent cooperative recurrence: 64 blocks x 512 threads, 254 grid syncs
  {
    const u16* sfp = sf;
    u16* hsp = hs;
    void* kargs[] = {
      (void*)&src, (void*)&text, (void*)&embt,
      (void*)&WhF, (void*)&bh2h, (void*)&wsc,
      (void*)&WgF, (void*)&b_ih, (void*)&b_hh,
      (void*)&sfp, (void*)&cbuf, (void*)&X0, (void*)&X1, (void*)&hsp
    };
    hipLaunchCooperativeKernel((const void*)k_loop, dim3(64), dim3(512),
                               kargs, 0, stream);
  }

  dim3 g2(B_*T_/64, (NC+63)/64);
  gemm_probs<<<g2, 256, 0, stream>>>(hs, Wgen, bgen, out, B_*T_, NC, H_);
}